// Round 6
// baseline (65.139 us; speedup 1.0000x reference)
//
#include <hip/hip_runtime.h>

#define NB  16
#define NTQ 64
#define NTV 256
#define ND  512
#define NU  512

typedef _Float16 half8_t __attribute__((ext_vector_type(8)));
typedef _Float16 half2_t __attribute__((ext_vector_type(2)));
typedef float floatx4 __attribute__((ext_vector_type(4)));

#if __has_builtin(__builtin_amdgcn_fdot2)
#define FDOT2(a, b, c) __builtin_amdgcn_fdot2((a), (b), (c), false)
#else
#define FDOT2(a, b, c) ((c) + (float)((a)[0]) * (float)((b)[0]) + (float)((a)[1]) * (float)((b)[1]))
#endif
#if __has_builtin(__builtin_amdgcn_rcph)
#define RCPH(x) ((_Float16)__builtin_amdgcn_rcph((_Float16)(x)))
#else
#define RCPH(x) ((_Float16)__builtin_amdgcn_rcpf((float)(x)))
#endif

__device__ __forceinline__ float wred_sum(float x) {
#pragma unroll
    for (int m = 1; m < 64; m <<= 1) x += __shfl_xor(x, m, 64);
    return x;
}
__device__ __forceinline__ float wred_max(float x) {
#pragma unroll
    for (int m = 1; m < 64; m <<= 1) x = fmaxf(x, __shfl_xor(x, m, 64));
    return x;
}

// ---------------- K1: prep (transpose W1/W2 -> f16, convert query/values -> f16, CVb, Vwh)
__global__ __launch_bounds__(256) void prep_kernel(
        const float* __restrict__ W1, const float* __restrict__ W2,
        const float* __restrict__ query, const float* __restrict__ values,
        const float* __restrict__ Vw, const float* __restrict__ Vb,
        _Float16* __restrict__ W1T, _Float16* __restrict__ W2T,
        _Float16* __restrict__ qh, _Float16* __restrict__ vh,
        _Float16* __restrict__ Vwh, float* __restrict__ CVb) {
    const int blk = blockIdx.x;
    const int t = threadIdx.x;
    __shared__ float tb[32][33];
    if (blk < 512) {
        const float* W = (blk < 256) ? W1 : W2;
        _Float16* WT = (blk < 256) ? W1T : W2T;
        const int tile = blk & 255;
        const int tr = tile >> 4, tc = tile & 15;
        const int c = t & 31, r8 = t >> 5;
#pragma unroll
        for (int i = 0; i < 4; ++i) {
            int r = r8 + 8 * i;
            tb[r][c] = W[(tr * 32 + r) * 512 + tc * 32 + c];
        }
        __syncthreads();
#pragma unroll
        for (int i = 0; i < 4; ++i) {
            int r = r8 + 8 * i;
            WT[(tc * 32 + r) * 512 + tr * 32 + c] = (_Float16)tb[c][r];
        }
    } else if (blk < 1792) {
        const bool isQ = blk < 768;
        const float* src = isQ ? query : values;
        _Float16* dst = isQ ? qh : vh;
        const int base = (isQ ? (blk - 512) : (blk - 768)) * 2048 + t * 8;
        float4 f0 = *(const float4*)(src + base);
        float4 f1 = *(const float4*)(src + base + 4);
        half8_t h;
        h[0] = (_Float16)f0.x; h[1] = (_Float16)f0.y;
        h[2] = (_Float16)f0.z; h[3] = (_Float16)f0.w;
        h[4] = (_Float16)f1.x; h[5] = (_Float16)f1.y;
        h[6] = (_Float16)f1.z; h[7] = (_Float16)f1.w;
        *(half8_t*)(dst + base) = h;
    } else {
        const float v0 = Vw[t], v1 = Vw[t + 256];
        Vwh[t] = (_Float16)v0;
        Vwh[t + 256] = (_Float16)v1;
        float s = wred_sum(v0 + v1);
        const int l = t & 63, w = t >> 6;
        __shared__ float ws4[4];
        if (l == 0) ws4[w] = s;
        __syncthreads();
        if (t == 0) CVb[0] = ws4[0] + ws4[1] + ws4[2] + ws4[3] + Vb[0];
    }
}

// ---------------- K2: fused projections, f16 MFMA; epilogue writes f16 exp2 (clamped):
// bid < 32 : Eqh[m=(b,q)][u] = f16(min(exp2(KC*(query@W1 + b1)), 60000))      [M=1024,N=512]
// bid >= 32: Evp[b][v][u]    = f16(min(exp2(KC*(values@W2 + b2)), 60000))     [M=256, N=512] v-MAJOR
// v-side got v-major for free by using A=values(v rows), B=W2T(u cols).
// Both sides: bias per COLUMN (gc = u).   KC = 2*log2(e); e^{2(qp+vp)} = Eq*Ev.
__global__ __launch_bounds__(256) void proj_gemm_kernel(
        const _Float16* __restrict__ qh, const _Float16* __restrict__ vh,
        const _Float16* __restrict__ W1T, const _Float16* __restrict__ W2T,
        const float* __restrict__ b1, const float* __restrict__ b2,
        _Float16* __restrict__ Eqh, _Float16* __restrict__ Evp) {
    __shared__ __align__(16) _Float16 As[128 * 40];
    __shared__ __align__(16) _Float16 Bs[128 * 40];
    const float KC = 2.8853900817779268f;  // 2*log2(e)
    const int bid = blockIdx.x;
    const int t = threadIdx.x;
    const int l = t & 63, w = t >> 6;

    const _Float16* Ag; const _Float16* Bg;
    const float* bias; _Float16* Cg;
    int tm, tn;
    if (bid < 32) {
        tm = (bid >> 2) * 128; tn = (bid & 3) * 128;
        Ag = qh; Bg = W1T; bias = b1; Cg = Eqh;
    } else {
        const int v = bid - 32;
        const int bb = v >> 3, r = v & 7;
        tm = (r & 1) * 128; tn = (r >> 1) * 128;
        Ag = vh + bb * (NTV * ND); Bg = W2T; bias = b2;
        Cg = Evp + bb * (NTV * NU);
    }

    floatx4 acc[4][4] = {};

    const int srow = t >> 1, spart = (t & 1) * 16;
    const int wm = (w >> 1) * 64, wn = (w & 1) * 64;
    const int lr = l & 15, lk = l >> 4;

    for (int kk = 0; kk < 512; kk += 32) {
        __syncthreads();
        half8_t a0 = *(const half8_t*)(Ag + (tm + srow) * 512 + kk + spart);
        half8_t a1 = *(const half8_t*)(Ag + (tm + srow) * 512 + kk + spart + 8);
        half8_t bb0 = *(const half8_t*)(Bg + (tn + srow) * 512 + kk + spart);
        half8_t bb1 = *(const half8_t*)(Bg + (tn + srow) * 512 + kk + spart + 8);
        *(half8_t*)(As + srow * 40 + spart) = a0;
        *(half8_t*)(As + srow * 40 + spart + 8) = a1;
        *(half8_t*)(Bs + srow * 40 + spart) = bb0;
        *(half8_t*)(Bs + srow * 40 + spart + 8) = bb1;
        __syncthreads();
        half8_t af[4], bf[4];
#pragma unroll
        for (int i = 0; i < 4; ++i)
            af[i] = *(const half8_t*)(As + (wm + 16 * i + lr) * 40 + lk * 8);
#pragma unroll
        for (int j = 0; j < 4; ++j)
            bf[j] = *(const half8_t*)(Bs + (wn + 16 * j + lr) * 40 + lk * 8);
#pragma unroll
        for (int i = 0; i < 4; ++i)
#pragma unroll
            for (int j = 0; j < 4; ++j)
                acc[i][j] = __builtin_amdgcn_mfma_f32_16x16x32_f16(af[i], bf[j], acc[i][j], 0, 0, 0);
    }

    // C/D layout: col = lane&15, row = (lane>>4)*4 + reg
#pragma unroll
    for (int i = 0; i < 4; ++i) {
#pragma unroll
        for (int j = 0; j < 4; ++j) {
            const int gr0 = tm + wm + 16 * i + lk * 4;
            const int gc = tn + wn + 16 * j + lr;
            const float bv = bias[gc];
#pragma unroll
            for (int r = 0; r < 4; ++r) {
                const float e = __builtin_amdgcn_exp2f(KC * (acc[i][j][r] + bv));
                Cg[(gr0 + r) * NU + gc] = (_Float16)fminf(e, 60000.f);
            }
        }
    }
}

// ---------------- K3: fused score + mask + softmax + context; 4 q/block, grid 256.
// Thread (qh = t>>8, v = t&255) owns the FULL u-sum for one (q,v):
//   per u-pair: v_pk_fma_f16 (p = eq*ev + 1), 2x v_rcp_f16, v_dot2_f32_f16 (acc += vw*r)
//   => 1 VALU + 1 trans per element; no cross-thread score reduction at all.
// f16 saturation is graceful: p->inf => rcp->0 (true term < 1.5e-5); p->0 => sigma=1.
__global__ __launch_bounds__(1024) void score_kernel(
        const _Float16* __restrict__ Eqh, const _Float16* __restrict__ Evp,
        const _Float16* __restrict__ vh, const _Float16* __restrict__ Vwh,
        const int* __restrict__ enc_mask, const float* __restrict__ CVbp,
        float* __restrict__ out) {
    const int bid = blockIdx.x;
    const int b = bid & 15, qg = bid >> 4;   // batch-clustered for L2
    const int q0 = qg * 4;
    const int t = threadIdx.x;
    const int l = t & 63;
    const int qh = __builtin_amdgcn_readfirstlane(t >> 8);  // wave-uniform -> scalar loads
    const int v = t & 255;
    const int w4 = (t >> 6) & 3;

    __shared__ float attL[4][256];
    __shared__ float ctxp[4][4][516];
    __shared__ float rs[4][4], ss[4][4];

    // ---- score: full u-sum per (q,v)
    float sc;
    {
        const _Float16* eqp = Eqh + (b * NTQ + q0 + qh) * NU;   // uniform
        const _Float16* evr = Evp + (b * NTV + v) * NU;         // per-lane row
        float a0 = 0.f, a1 = 0.f, a2 = 0.f, a3 = 0.f;
#pragma unroll 2
        for (int u0 = 0; u0 < NU; u0 += 8) {
            const half8_t ev8 = *(const half8_t*)(evr + u0);
            const half8_t eq8 = *(const half8_t*)(eqp + u0);
            const half8_t vw8 = *(const half8_t*)(Vwh + u0);
            half2_t e0 = {eq8[0], eq8[1]}, e1 = {eq8[2], eq8[3]},
                    e2 = {eq8[4], eq8[5]}, e3 = {eq8[6], eq8[7]};
            half2_t v0 = {ev8[0], ev8[1]}, v1 = {ev8[2], ev8[3]},
                    v2 = {ev8[4], ev8[5]}, v3 = {ev8[6], ev8[7]};
            half2_t w0 = {vw8[0], vw8[1]}, w1 = {vw8[2], vw8[3]},
                    w2 = {vw8[4], vw8[5]}, w3 = {vw8[6], vw8[7]};
            const half2_t one2 = {(_Float16)1.0f, (_Float16)1.0f};
            half2_t p0 = e0 * v0 + one2;
            half2_t p1 = e1 * v1 + one2;
            half2_t p2 = e2 * v2 + one2;
            half2_t p3 = e3 * v3 + one2;
            half2_t r0 = {RCPH(p0[0]), RCPH(p0[1])};
            half2_t r1 = {RCPH(p1[0]), RCPH(p1[1])};
            half2_t r2 = {RCPH(p2[0]), RCPH(p2[1])};
            half2_t r3 = {RCPH(p3[0]), RCPH(p3[1])};
            a0 = FDOT2(w0, r0, a0);
            a1 = FDOT2(w1, r1, a1);
            a2 = FDOT2(w2, r2, a2);
            a3 = FDOT2(w3, r3, a3);
        }
        sc = CVbp[0] - 2.f * ((a0 + a1) + (a2 + a3));
        sc -= enc_mask[b * NTV + v] ? 0.f : 1e9f;
    }

    // ---- softmax over v (4 waves per qh group)
    float ee;
    {
        float m = wred_max(sc);
        if (l == 0) rs[qh][w4] = m;
    }
    __syncthreads();
    {
        const float m = fmaxf(fmaxf(rs[qh][0], rs[qh][1]), fmaxf(rs[qh][2], rs[qh][3]));
        const float LOG2E = 1.4426950408889634f;
        ee = __builtin_amdgcn_exp2f((sc - m) * LOG2E);
        float t0 = wred_sum(ee);
        if (l == 0) ss[qh][w4] = t0;
    }
    __syncthreads();
    {
        const float S = (ss[qh][0] + ss[qh][1]) + (ss[qh][2] + ss[qh][3]);
        const float a = ee * __builtin_amdgcn_rcpf(S);
        attL[qh][v] = a;
        float* out_attn = out + NB * NTQ * ND;
        out_attn[(b * NTQ + q0 + qh) * NTV + v] = a;
    }
    __syncthreads();

    // ---- context: thread (vg = t>>8, dx = t&255) does d = {2dx, 2dx+1}, all 4 q, v-range 64
    {
        const int vg = t >> 8;
        const int dx = t & 255;
        const _Float16* vsrc = vh + (b * NTV + vg * 64) * ND + dx * 2;
        float c0x = 0.f, c0y = 0.f, c1x = 0.f, c1y = 0.f;
        float c2x = 0.f, c2y = 0.f, c3x = 0.f, c3y = 0.f;
#pragma unroll 4
        for (int vi = 0; vi < 64; ++vi) {
            const half2_t vv = *(const half2_t*)(vsrc + vi * ND);
            const float vx = (float)vv[0], vy = (float)vv[1];
            const int vv_i = vg * 64 + vi;
            const float aw0 = attL[0][vv_i], aw1 = attL[1][vv_i];
            const float aw2 = attL[2][vv_i], aw3 = attL[3][vv_i];
            c0x = fmaf(aw0, vx, c0x); c0y = fmaf(aw0, vy, c0y);
            c1x = fmaf(aw1, vx, c1x); c1y = fmaf(aw1, vy, c1y);
            c2x = fmaf(aw2, vx, c2x); c2y = fmaf(aw2, vy, c2y);
            c3x = fmaf(aw3, vx, c3x); c3y = fmaf(aw3, vy, c3y);
        }
        *(float2*)&ctxp[0][vg][dx * 2] = make_float2(c0x, c0y);
        *(float2*)&ctxp[1][vg][dx * 2] = make_float2(c1x, c1y);
        *(float2*)&ctxp[2][vg][dx * 2] = make_float2(c2x, c2y);
        *(float2*)&ctxp[3][vg][dx * 2] = make_float2(c3x, c3y);
    }
    __syncthreads();
#pragma unroll
    for (int k = 0; k < 2; ++k) {
        const int idx = t + k * 1024;
        const int cq = idx >> 9, d = idx & 511;
        float s = (ctxp[cq][0][d] + ctxp[cq][1][d]) + (ctxp[cq][2][d] + ctxp[cq][3][d]);
        out[(b * NTQ + q0 + cq) * ND + d] = s;
    }
}

extern "C" void kernel_launch(void* const* d_in, const int* in_sizes, int n_in,
                              void* d_out, int out_size, void* d_ws, size_t ws_size,
                              hipStream_t stream) {
    const float* query  = (const float*)d_in[0];
    const float* values = (const float*)d_in[1];
    const int*   emask  = (const int*)d_in[2];
    const float* W1     = (const float*)d_in[3];
    const float* b1     = (const float*)d_in[4];
    const float* W2     = (const float*)d_in[5];
    const float* b2     = (const float*)d_in[6];
    const float* Vw     = (const float*)d_in[7];
    const float* Vb     = (const float*)d_in[8];
    float* out = (float*)d_out;

    char* ws = (char*)d_ws;
    _Float16* W1T = (_Float16*)(ws + 0);          //  512 KB [U][D] f16
    _Float16* W2T = (_Float16*)(ws + 524288);     //  512 KB [U][D] f16
    _Float16* qh  = (_Float16*)(ws + 1048576);    //    1 MB [B*TQ][D] f16
    _Float16* vh  = (_Float16*)(ws + 2097152);    //    4 MB [B*TV][D] f16
    _Float16* Eqh = (_Float16*)(ws + 6291456);    //    1 MB [B*TQ][U] f16 exp2
    _Float16* Evp = (_Float16*)(ws + 7340032);    //    4 MB [B][TV][U] f16 exp2 (v-major)
    _Float16* Vwh = (_Float16*)(ws + 11534336);   //    1 KB [U] f16
    float* CVb    = (float*)(ws + 11539456);      //    4 B

    prep_kernel<<<dim3(1793), dim3(256), 0, stream>>>(W1, W2, query, values, Vw, Vb,
                                                      W1T, W2T, qh, vh, Vwh, CVb);
    proj_gemm_kernel<<<dim3(160), dim3(256), 0, stream>>>(qh, vh, W1T, W2T, b1, b2, Eqh, Evp);
    score_kernel<<<dim3(256), dim3(1024), 0, stream>>>(Eqh, Evp, vh, Vwh, emask, CVb, out);
}

// Round 7
// 59.846 us; speedup vs baseline: 1.0884x; 1.0884x over previous
//
#include <hip/hip_runtime.h>

#define NB  16
#define NTQ 64
#define NTV 256
#define ND  512
#define NU  512

typedef _Float16 half8_t __attribute__((ext_vector_type(8)));
typedef _Float16 half2_t __attribute__((ext_vector_type(2)));
typedef float floatx4 __attribute__((ext_vector_type(4)));

#if __has_builtin(__builtin_amdgcn_fdot2)
#define FDOT2(a, b, c) __builtin_amdgcn_fdot2((a), (b), (c), false)
#else
#define FDOT2(a, b, c) ((c) + (float)((a)[0]) * (float)((b)[0]) + (float)((a)[1]) * (float)((b)[1]))
#endif
#if __has_builtin(__builtin_amdgcn_rcph)
#define RCPH(x) ((_Float16)__builtin_amdgcn_rcph((_Float16)(x)))
#else
#define RCPH(x) ((_Float16)__builtin_amdgcn_rcpf((float)(x)))
#endif

__device__ __forceinline__ float wred_sum(float x) {
#pragma unroll
    for (int m = 1; m < 64; m <<= 1) x += __shfl_xor(x, m, 64);
    return x;
}
__device__ __forceinline__ float wred_max(float x) {
#pragma unroll
    for (int m = 1; m < 64; m <<= 1) x = fmaxf(x, __shfl_xor(x, m, 64));
    return x;
}

// ---------------- K1: prep (transpose W1/W2 -> f16, convert query/values -> f16, CVb, Vwh)
__global__ __launch_bounds__(256) void prep_kernel(
        const float* __restrict__ W1, const float* __restrict__ W2,
        const float* __restrict__ query, const float* __restrict__ values,
        const float* __restrict__ Vw, const float* __restrict__ Vb,
        _Float16* __restrict__ W1T, _Float16* __restrict__ W2T,
        _Float16* __restrict__ qh, _Float16* __restrict__ vh,
        _Float16* __restrict__ Vwh, float* __restrict__ CVb) {
    const int blk = blockIdx.x;
    const int t = threadIdx.x;
    __shared__ float tb[32][33];
    if (blk < 512) {
        const float* W = (blk < 256) ? W1 : W2;
        _Float16* WT = (blk < 256) ? W1T : W2T;
        const int tile = blk & 255;
        const int tr = tile >> 4, tc = tile & 15;
        const int c = t & 31, r8 = t >> 5;
#pragma unroll
        for (int i = 0; i < 4; ++i) {
            int r = r8 + 8 * i;
            tb[r][c] = W[(tr * 32 + r) * 512 + tc * 32 + c];
        }
        __syncthreads();
#pragma unroll
        for (int i = 0; i < 4; ++i) {
            int r = r8 + 8 * i;
            WT[(tc * 32 + r) * 512 + tr * 32 + c] = (_Float16)tb[c][r];
        }
    } else if (blk < 1792) {
        const bool isQ = blk < 768;
        const float* src = isQ ? query : values;
        _Float16* dst = isQ ? qh : vh;
        const int base = (isQ ? (blk - 512) : (blk - 768)) * 2048 + t * 8;
        float4 f0 = *(const float4*)(src + base);
        float4 f1 = *(const float4*)(src + base + 4);
        half8_t h;
        h[0] = (_Float16)f0.x; h[1] = (_Float16)f0.y;
        h[2] = (_Float16)f0.z; h[3] = (_Float16)f0.w;
        h[4] = (_Float16)f1.x; h[5] = (_Float16)f1.y;
        h[6] = (_Float16)f1.z; h[7] = (_Float16)f1.w;
        *(half8_t*)(dst + base) = h;
    } else {
        const float v0 = Vw[t], v1 = Vw[t + 256];
        Vwh[t] = (_Float16)v0;
        Vwh[t + 256] = (_Float16)v1;
        float s = wred_sum(v0 + v1);
        const int l = t & 63, w = t >> 6;
        __shared__ float ws4[4];
        if (l == 0) ws4[w] = s;
        __syncthreads();
        if (t == 0) CVb[0] = ws4[0] + ws4[1] + ws4[2] + ws4[3] + Vb[0];
    }
}

// ---------------- K2: fused projections, f16 MFMA; epilogue writes f16 exp2 (clamped):
// bid < 32 : Eqh[m=(b,q)][u] = f16(min(exp2(KC*(query@W1 + b1)), 60000))      [M=1024,N=512]
// bid >= 32: Evp[b][v][u]    = f16(min(exp2(KC*(values@W2 + b2)), 60000))     [M=256, N=512] v-MAJOR
__global__ __launch_bounds__(256) void proj_gemm_kernel(
        const _Float16* __restrict__ qh, const _Float16* __restrict__ vh,
        const _Float16* __restrict__ W1T, const _Float16* __restrict__ W2T,
        const float* __restrict__ b1, const float* __restrict__ b2,
        _Float16* __restrict__ Eqh, _Float16* __restrict__ Evp) {
    __shared__ __align__(16) _Float16 As[128 * 40];
    __shared__ __align__(16) _Float16 Bs[128 * 40];
    const float KC = 2.8853900817779268f;  // 2*log2(e)
    const int bid = blockIdx.x;
    const int t = threadIdx.x;
    const int l = t & 63, w = t >> 6;

    const _Float16* Ag; const _Float16* Bg;
    const float* bias; _Float16* Cg;
    int tm, tn;
    if (bid < 32) {
        tm = (bid >> 2) * 128; tn = (bid & 3) * 128;
        Ag = qh; Bg = W1T; bias = b1; Cg = Eqh;
    } else {
        const int v = bid - 32;
        const int bb = v >> 3, r = v & 7;
        tm = (r & 1) * 128; tn = (r >> 1) * 128;
        Ag = vh + bb * (NTV * ND); Bg = W2T; bias = b2;
        Cg = Evp + bb * (NTV * NU);
    }

    floatx4 acc[4][4] = {};

    const int srow = t >> 1, spart = (t & 1) * 16;
    const int wm = (w >> 1) * 64, wn = (w & 1) * 64;
    const int lr = l & 15, lk = l >> 4;

    for (int kk = 0; kk < 512; kk += 32) {
        __syncthreads();
        half8_t a0 = *(const half8_t*)(Ag + (tm + srow) * 512 + kk + spart);
        half8_t a1 = *(const half8_t*)(Ag + (tm + srow) * 512 + kk + spart + 8);
        half8_t bb0 = *(const half8_t*)(Bg + (tn + srow) * 512 + kk + spart);
        half8_t bb1 = *(const half8_t*)(Bg + (tn + srow) * 512 + kk + spart + 8);
        *(half8_t*)(As + srow * 40 + spart) = a0;
        *(half8_t*)(As + srow * 40 + spart + 8) = a1;
        *(half8_t*)(Bs + srow * 40 + spart) = bb0;
        *(half8_t*)(Bs + srow * 40 + spart + 8) = bb1;
        __syncthreads();
        half8_t af[4], bf[4];
#pragma unroll
        for (int i = 0; i < 4; ++i)
            af[i] = *(const half8_t*)(As + (wm + 16 * i + lr) * 40 + lk * 8);
#pragma unroll
        for (int j = 0; j < 4; ++j)
            bf[j] = *(const half8_t*)(Bs + (wn + 16 * j + lr) * 40 + lk * 8);
#pragma unroll
        for (int i = 0; i < 4; ++i)
#pragma unroll
            for (int j = 0; j < 4; ++j)
                acc[i][j] = __builtin_amdgcn_mfma_f32_16x16x32_f16(af[i], bf[j], acc[i][j], 0, 0, 0);
    }

    // C/D layout: col = lane&15, row = (lane>>4)*4 + reg
#pragma unroll
    for (int i = 0; i < 4; ++i) {
#pragma unroll
        for (int j = 0; j < 4; ++j) {
            const int gr0 = tm + wm + 16 * i + lk * 4;
            const int gc = tn + wn + 16 * j + lr;
            const float bv = bias[gc];
#pragma unroll
            for (int r = 0; r < 4; ++r) {
                const float e = __builtin_amdgcn_exp2f(KC * (acc[i][j][r] + bv));
                Cg[(gr0 + r) * NU + gc] = (_Float16)fminf(e, 60000.f);
            }
        }
    }
}

// ---------------- K3a: score + mask + softmax + attn-out. Grid 512 (b, qpair), 1024 thr.
// Wave-cooperative rows: wave (qh = w&1, vslice = w>>1) streams 32 Evp rows; per row the
// 64 lanes load 16B each (1 KB row, perfectly coalesced), each lane covers 8 u's
// (4 pk_fma + 8 rcp_f16 + 4 fdot2), then wred_sum folds 64 partials into the score.
// eq8/vw8 are per-lane FIXED -> loaded once into regs. Iterations independent -> prefetch.
__global__ __launch_bounds__(1024, 8) void score_kernel(
        const _Float16* __restrict__ Eqh, const _Float16* __restrict__ Evp,
        const _Float16* __restrict__ Vwh, const int* __restrict__ enc_mask,
        const float* __restrict__ CVbp, float* __restrict__ out) {
    const int bid = blockIdx.x;
    const int b = bid & 15, qp = bid >> 4;   // batch b -> XCD b%8; qp 0..31
    const int q0 = qp * 2;
    const int t = threadIdx.x;
    const int w = t >> 6, l = t & 63;
    const int qh = w & 1;                    // wave's q
    const int vs = w >> 1;                   // wave's v-slice (32 rows)

    __shared__ float scL[2][256];
    __shared__ float rs[2][4], ss[2][4];

    // per-lane fixed operand slices (u = l*8 .. l*8+7)
    const half8_t eq8 = *(const half8_t*)(Eqh + (b * NTQ + q0 + qh) * NU + l * 8);
    const half8_t vw8 = *(const half8_t*)(Vwh + l * 8);
    const half2_t e0 = {eq8[0], eq8[1]}, e1 = {eq8[2], eq8[3]},
                  e2 = {eq8[4], eq8[5]}, e3 = {eq8[6], eq8[7]};
    const half2_t w0 = {vw8[0], vw8[1]}, w1 = {vw8[2], vw8[3]},
                  w2 = {vw8[4], vw8[5]}, w3 = {vw8[6], vw8[7]};
    const half2_t one2 = {(_Float16)1.0f, (_Float16)1.0f};

    const _Float16* evb = Evp + (b * NTV + vs * 32) * NU + l * 8;
#pragma unroll 2
    for (int r = 0; r < 32; ++r) {
        const half8_t ev8 = *(const half8_t*)(evb + r * NU);
        const half2_t v0 = {ev8[0], ev8[1]}, v1 = {ev8[2], ev8[3]},
                      v2 = {ev8[4], ev8[5]}, v3 = {ev8[6], ev8[7]};
        const half2_t p0 = e0 * v0 + one2;
        const half2_t p1 = e1 * v1 + one2;
        const half2_t p2 = e2 * v2 + one2;
        const half2_t p3 = e3 * v3 + one2;
        const half2_t r0 = {RCPH(p0[0]), RCPH(p0[1])};
        const half2_t r1 = {RCPH(p1[0]), RCPH(p1[1])};
        const half2_t r2 = {RCPH(p2[0]), RCPH(p2[1])};
        const half2_t r3 = {RCPH(p3[0]), RCPH(p3[1])};
        float a0 = FDOT2(w0, r0, 0.f);
        a0 = FDOT2(w1, r1, a0);
        float a1 = FDOT2(w2, r2, 0.f);
        a1 = FDOT2(w3, r3, a1);
        float s = wred_sum(a0 + a1);
        if (l == 0) scL[qh][vs * 32 + r] = s;
    }
    __syncthreads();

    // ---- softmax over v (threads 0..511: q = t>>8, v = t&255)
    if (t < 512) {
        const int q = t >> 8, v = t & 255;
        const int ll = t & 63, w4 = (t >> 6) & 3;
        float sc = CVbp[0] - 2.f * scL[q][v];
        sc -= enc_mask[b * NTV + v] ? 0.f : 1e9f;
        float m = wred_max(sc);
        if (ll == 0) rs[q][w4] = m;
        __syncthreads();
        m = fmaxf(fmaxf(rs[q][0], rs[q][1]), fmaxf(rs[q][2], rs[q][3]));
        const float LOG2E = 1.4426950408889634f;
        const float ee = __builtin_amdgcn_exp2f((sc - m) * LOG2E);
        float t0 = wred_sum(ee);
        if (ll == 0) ss[q][w4] = t0;
        __syncthreads();
        const float S = (ss[q][0] + ss[q][1]) + (ss[q][2] + ss[q][3]);
        const float a = ee * __builtin_amdgcn_rcpf(S);
        float* out_attn = out + NB * NTQ * ND;
        out_attn[(b * NTQ + q0 + q) * NTV + v] = a;
    } else {
        __syncthreads();
        __syncthreads();
    }
}

// ---------------- K3b: context = attn @ values (f16 vh). Grid 256 (b, qquad), 1024 thr.
// Stages attn (4x256 f32) in LDS; thread (vg = t>>8, dp = t&255) streams 64 v's with
// coalesced half2 loads of vh, all 4 q's per thread; LDS partial reduce.
__global__ __launch_bounds__(1024) void ctx_kernel(
        const _Float16* __restrict__ vh, float* __restrict__ out) {
    const int bid = blockIdx.x;
    const int b = bid & 15, qq = bid >> 4;   // q0 = qq*4
    const int q0 = qq * 4;
    const int t = threadIdx.x;

    __shared__ float attL[4][256];
    __shared__ float ctxp[4][4][516];

    const float* attn_in = out + NB * NTQ * ND;
    attL[t >> 8][t & 255] = attn_in[(b * NTQ + q0 + (t >> 8)) * NTV + (t & 255)];
    __syncthreads();

    {
        const int vg = t >> 8;           // 0..3 (64 v each)
        const int dp = t & 255;          // d = 2dp, 2dp+1
        const _Float16* vsrc = vh + (b * NTV + vg * 64) * ND + dp * 2;
        float c0x = 0.f, c0y = 0.f, c1x = 0.f, c1y = 0.f;
        float c2x = 0.f, c2y = 0.f, c3x = 0.f, c3y = 0.f;
#pragma unroll 4
        for (int vi = 0; vi < 64; ++vi) {
            const half2_t vv = *(const half2_t*)(vsrc + vi * ND);
            const float vx = (float)vv[0], vy = (float)vv[1];
            const int v = vg * 64 + vi;
            const float aw0 = attL[0][v], aw1 = attL[1][v];
            const float aw2 = attL[2][v], aw3 = attL[3][v];
            c0x = fmaf(aw0, vx, c0x); c0y = fmaf(aw0, vy, c0y);
            c1x = fmaf(aw1, vx, c1x); c1y = fmaf(aw1, vy, c1y);
            c2x = fmaf(aw2, vx, c2x); c2y = fmaf(aw2, vy, c2y);
            c3x = fmaf(aw3, vx, c3x); c3y = fmaf(aw3, vy, c3y);
        }
        *(float2*)&ctxp[0][vg][dp * 2] = make_float2(c0x, c0y);
        *(float2*)&ctxp[1][vg][dp * 2] = make_float2(c1x, c1y);
        *(float2*)&ctxp[2][vg][dp * 2] = make_float2(c2x, c2y);
        *(float2*)&ctxp[3][vg][dp * 2] = make_float2(c3x, c3y);
    }
    __syncthreads();
#pragma unroll
    for (int k = 0; k < 2; ++k) {
        const int idx = t + k * 1024;
        const int cq = idx >> 9, d = idx & 511;
        float s = (ctxp[cq][0][d] + ctxp[cq][1][d]) + (ctxp[cq][2][d] + ctxp[cq][3][d]);
        out[(b * NTQ + q0 + cq) * ND + d] = s;
    }
}

extern "C" void kernel_launch(void* const* d_in, const int* in_sizes, int n_in,
                              void* d_out, int out_size, void* d_ws, size_t ws_size,
                              hipStream_t stream) {
    const float* query  = (const float*)d_in[0];
    const float* values = (const float*)d_in[1];
    const int*   emask  = (const int*)d_in[2];
    const float* W1     = (const float*)d_in[3];
    const float* b1     = (const float*)d_in[4];
    const float* W2     = (const float*)d_in[5];
    const float* b2     = (const float*)d_in[6];
    const float* Vw     = (const float*)d_in[7];
    const float* Vb     = (const float*)d_in[8];
    float* out = (float*)d_out;

    char* ws = (char*)d_ws;
    _Float16* W1T = (_Float16*)(ws + 0);          //  512 KB [U][D] f16
    _Float16* W2T = (_Float16*)(ws + 524288);     //  512 KB [U][D] f16
    _Float16* qh  = (_Float16*)(ws + 1048576);    //    1 MB [B*TQ][D] f16
    _Float16* vh  = (_Float16*)(ws + 2097152);    //    4 MB [B*TV][D] f16
    _Float16* Eqh = (_Float16*)(ws + 6291456);    //    1 MB [B*TQ][U] f16 exp2
    _Float16* Evp = (_Float16*)(ws + 7340032);    //    4 MB [B][TV][U] f16 exp2 (v-major)
    _Float16* Vwh = (_Float16*)(ws + 11534336);   //    1 KB [U] f16
    float* CVb    = (float*)(ws + 11539456);      //    4 B

    prep_kernel<<<dim3(1793), dim3(256), 0, stream>>>(W1, W2, query, values, Vw, Vb,
                                                      W1T, W2T, qh, vh, Vwh, CVb);
    proj_gemm_kernel<<<dim3(160), dim3(256), 0, stream>>>(qh, vh, W1T, W2T, b1, b2, Eqh, Evp);
    score_kernel<<<dim3(512), dim3(1024), 0, stream>>>(Eqh, Evp, Vwh, emask, CVb, out);
    ctx_kernel<<<dim3(256), dim3(1024), 0, stream>>>(vh, out);
}